// Round 12
// baseline (431.651 us; speedup 1.0000x reference)
//
#include <hip/hip_runtime.h>

#define NN 20000
#define EE 320000

typedef unsigned int  u32;
typedef unsigned short u16;

typedef _Float16 h8 __attribute__((ext_vector_type(8)));
typedef _Float16 h2 __attribute__((ext_vector_type(2)));
typedef float    f4 __attribute__((ext_vector_type(4)));

union U16 { uint4 u; h8 h; };

__device__ inline u32 phh(float a, float b){
  h2 v; v[0] = (_Float16)a; v[1] = (_Float16)b;
  return __builtin_bit_cast(u32, v);
}
__device__ inline u16 f2h_u(float a){
  _Float16 h = (_Float16)a;
  return __builtin_bit_cast(u16, h);
}
__device__ inline float2 up2(u32 u){
  h2 v = __builtin_bit_cast(h2, u);
  return make_float2((float)v[0], (float)v[1]);
}
__device__ inline h8 pack8(float4 a, float4 b){
  U16 t;
  t.u.x = phh(a.x, a.y);
  t.u.y = phh(a.z, a.w);
  t.u.z = phh(b.x, b.y);
  t.u.w = phh(b.z, b.w);
  return t.h;
}

// ---------------------------------------------------------------------------
// k0: pack all weights into MFMA fragment order, f16.
// Frag layout (16x16x32): lane holds M[k=(lane/16)*8+j][c=ct*16+lane%16].
// ws (u16 units):
//   [0,65536)        W2pack: [d][ct(8)][ks(4)][lane(64)][j(8)]  (c 0-63=Wq, 64-127=Wk[d])
//   [65536,73728)    mw1pack: [ct(8)][ks(2)][lane][j]   (K=64) — stays GLOBAL (L1-hot)
//   [73728,90112)    mw2pack  ┐
//   [90112,106496)   mt1pack  ├ staged into k2's LDS (96KB)
//   [106496,122880)  mt2pack  ┘
// ---------------------------------------------------------------------------
__global__ void k0_pack(const float* __restrict__ Wq, const float* __restrict__ Wk,
                        const float* __restrict__ w1w, const float* __restrict__ w2w,
                        const float* __restrict__ w1t, const float* __restrict__ w2t,
                        u16* __restrict__ pack)
{
  const int tot = 65536 + 8192 + 16384*3;
  for (int o = blockIdx.x*blockDim.x + threadIdx.x; o < tot; o += gridDim.x*blockDim.x){
    float v;
    if (o < 65536){
      int d = o >> 14, r = o & 16383;
      int ct = r >> 11, ks = (r >> 9) & 3, lane = (r >> 3) & 63, j = r & 7;
      int k = ks*32 + (lane >> 4)*8 + j, c = ct*16 + (lane & 15);
      v = (c < 64) ? Wq[k*64 + c] : Wk[((d << 7) + k)*64 + (c - 64)];
    } else if (o < 73728){
      int r = o - 65536;
      int ct = r >> 10, ks = (r >> 9) & 1, lane = (r >> 3) & 63, j = r & 7;
      int k = ks*32 + (lane >> 4)*8 + j, c = ct*16 + (lane & 15);
      v = w1w[k*128 + c];
    } else {
      int r = o - 73728;
      int m = r >> 14; r &= 16383;
      int ct = r >> 11, ks = (r >> 9) & 3, lane = (r >> 3) & 63, j = r & 7;
      int k = ks*32 + (lane >> 4)*8 + j, c = ct*16 + (lane & 15);
      const float* M = (m == 0) ? w2w : (m == 1) ? w1t : w2t;
      v = M[k*128 + c];
    }
    pack[o] = f2h_u(v);
  }
}

// ---------------------------------------------------------------------------
// k1: per-d projection GEMM: [N x 128] @ [128 x 128] -> q||k per node, f16.
// ---------------------------------------------------------------------------
__global__ __launch_bounds__(256) void k1_proj(const float* __restrict__ X,
    const u16* __restrict__ wpack, u16* __restrict__ Q, u16* __restrict__ Kv)
{
  const int d = blockIdx.y;
  const int nBase = blockIdx.x * 64;
  const int wv = threadIdx.x >> 6;
  const int l  = threadIdx.x & 63;
  const int row16 = l & 15, g = l >> 4;
  int node_a = nBase + wv*16 + row16;
  int na = node_a < NN ? node_a : NN-1;          // clamp; stores are guarded
  const float* xrow = X + ((size_t)d*NN + na)*128;
  h8 a[4];
  #pragma unroll
  for (int ks = 0; ks < 4; ks++){
    float4 f0 = *(const float4*)(xrow + ks*32 + g*8);
    float4 f1 = *(const float4*)(xrow + ks*32 + g*8 + 4);
    a[ks] = pack8(f0, f1);
  }
  const uint4* wp4 = (const uint4*)wpack;
  #pragma unroll
  for (int ct = 0; ct < 8; ct++){
    f4 acc = {0.f, 0.f, 0.f, 0.f};
    #pragma unroll
    for (int ks = 0; ks < 4; ks++){
      U16 b; b.u = wp4[((d*8 + ct)*4 + ks)*64 + l];
      acc = __builtin_amdgcn_mfma_f32_16x16x32_f16(a[ks], b.h, acc, 0, 0, 0);
    }
    u16* dst = (ct < 4) ? Q : Kv;
    int cc = (ct & 3)*16 + row16;
    #pragma unroll
    for (int r = 0; r < 4; r++){
      int node = nBase + wv*16 + g*4 + r;        // D: col=lane&15, row=(lane>>4)*4+r
      if (node < NN) dst[(size_t)node*256 + d*64 + cc] = f2h_u(acc[r]);
    }
  }
}

// ---------------------------------------------------------------------------
// k2_mlp v9: persistent-weights + fused gather/dot, 15-wave occupancy.
//  R12 change vs R9: mw1 (16KB) evicted from LDS to global (L1-resident) so
//  LDS drops to 96KB weights + 2KB bias + 15x4KB hidden = 158KB -> one
//  960-thread block per CU = 15 waves/CU (~47% occ, was 8 waves/21%).
//  launch_bounds(960,4) caps VGPR at 128 (R9 compiled at exactly 128).
//  nt hints reverted (R11: gfx950 nt = cache bypass -> 4x read amplification).
// ---------------------------------------------------------------------------
#define MW2_4 0
#define MT1_4 2048
#define MT2_4 4096

#define TLOAD(TF0,TF1,TF2,TF3,TIDX)                                             \
{                                                                               \
  const float* trow_ = T + (size_t)((TIDX)*16 + e16)*128;                       \
  float4 a_, b_;                                                                \
  a_ = *(const float4*)(trow_ +  0 + g*8); b_ = *(const float4*)(trow_ +  0 + g*8 + 4); TF0 = pack8(a_,b_); \
  a_ = *(const float4*)(trow_ + 32 + g*8); b_ = *(const float4*)(trow_ + 32 + g*8 + 4); TF1 = pack8(a_,b_); \
  a_ = *(const float4*)(trow_ + 64 + g*8); b_ = *(const float4*)(trow_ + 64 + g*8 + 4); TF2 = pack8(a_,b_); \
  a_ = *(const float4*)(trow_ + 96 + g*8); b_ = *(const float4*)(trow_ + 96 + g*8 + 4); TF3 = pack8(a_,b_); \
}

#define GLOAD(TIDX)                                                             \
{                                                                               \
  const int e_ = (TIDX)*16 + e16;                                               \
  const int nj_ = eidx[e_];                                                     \
  const int ni_ = eidx[EE + e_];                                                \
  const u16* qb_ = Q  + ((size_t)ni_ << 8) + g*8;                               \
  const u16* kb_ = Kv + ((size_t)nj_ << 8) + g*8;                               \
  gq0.u = *(const uint4*)(qb_      );  gq1.u = *(const uint4*)(qb_ +  64);      \
  gq2.u = *(const uint4*)(qb_ + 128);  gq3.u = *(const uint4*)(qb_ + 192);      \
  gq4.u = *(const uint4*)(qb_ +  32);  gq5.u = *(const uint4*)(qb_ +  96);      \
  gq6.u = *(const uint4*)(qb_ + 160);  gq7.u = *(const uint4*)(qb_ + 224);      \
  gk0.u = *(const uint4*)(kb_      );  gk1.u = *(const uint4*)(kb_ +  64);      \
  gk2.u = *(const uint4*)(kb_ + 128);  gk3.u = *(const uint4*)(kb_ + 192);      \
  gk4.u = *(const uint4*)(kb_ +  32);  gk5.u = *(const uint4*)(kb_ +  96);      \
  gk6.u = *(const uint4*)(kb_ + 160);  gk7.u = *(const uint4*)(kb_ + 224);      \
}

#define DOT_HALF(Q0,Q1,Q2,Q3,K0,K1,K2,K3,WF)                                    \
{                                                                               \
  float s_[8];                                                                  \
  _Pragma("unroll")                                                             \
  for (int j = 0; j < 8; j++)                                                   \
    s_[j] = (float)Q0.h[j]*(float)K0.h[j] + (float)Q1.h[j]*(float)K1.h[j]       \
          + (float)Q2.h[j]*(float)K2.h[j] + (float)Q3.h[j]*(float)K3.h[j];      \
  U16 t_;                                                                       \
  t_.u.x = phh(s_[0],s_[1]); t_.u.y = phh(s_[2],s_[3]);                         \
  t_.u.z = phh(s_[4],s_[5]); t_.u.w = phh(s_[6],s_[7]);                         \
  WF = t_;                                                                      \
}

#define DOT2()                                                                  \
  DOT_HALF(gq0,gq1,gq2,gq3,gk0,gk1,gk2,gk3,wf0)                                 \
  DOT_HALF(gq4,gq5,gq6,gq7,gk4,gk5,gk6,gk7,wf1)

#define K2_TILE(TF0,TF1,TF2,TF3,TIDX)                                           \
{                                                                               \
  /* t-L1 -> hb */                                                              \
  _Pragma("unroll")                                                             \
  for (int ct = 0; ct < 8; ct++){                                               \
    U16 q0,q1,q2,q3;                                                            \
    q0.u = wlds4[MT1_4 + (ct*4+0)*64 + l];                                      \
    q1.u = wlds4[MT1_4 + (ct*4+1)*64 + l];                                      \
    q2.u = wlds4[MT1_4 + (ct*4+2)*64 + l];                                      \
    q3.u = wlds4[MT1_4 + (ct*4+3)*64 + l];                                      \
    f4 A = {0.f,0.f,0.f,0.f};                                                   \
    A = __builtin_amdgcn_mfma_f32_16x16x32_f16(q0.h, TF0, A, 0, 0, 0);          \
    A = __builtin_amdgcn_mfma_f32_16x16x32_f16(q1.h, TF1, A, 0, 0, 0);          \
    A = __builtin_amdgcn_mfma_f32_16x16x32_f16(q2.h, TF2, A, 0, 0, 0);          \
    A = __builtin_amdgcn_mfma_f32_16x16x32_f16(q3.h, TF3, A, 0, 0, 0);          \
    float4 bb = *(const float4*)&bias_lds[256 + ct*16 + g*4];                   \
    uint2 v;                                                                    \
    v.x = phh(fmaxf(A[0]+bb.x,0.f), fmaxf(A[1]+bb.y,0.f));                      \
    v.y = phh(fmaxf(A[2]+bb.z,0.f), fmaxf(A[3]+bb.w,0.f));                      \
    *(uint2*)&myhb[e16*128 + ((ct*16 + g*4) ^ swz)] = v;                        \
  }                                                                             \
  /* t-L2 -> accT (f16 packed, incl. b2t) */                                    \
  uint2 accT[8];                                                                \
  {                                                                             \
    U16 h0,h1,h2,h3;                                                            \
    h0.u = *(const uint4*)&myhb[e16*128 + (( 0 + g*8) ^ swz)];                  \
    h1.u = *(const uint4*)&myhb[e16*128 + ((32 + g*8) ^ swz)];                  \
    h2.u = *(const uint4*)&myhb[e16*128 + ((64 + g*8) ^ swz)];                  \
    h3.u = *(const uint4*)&myhb[e16*128 + ((96 + g*8) ^ swz)];                  \
    _Pragma("unroll")                                                           \
    for (int ct = 0; ct < 8; ct++){                                             \
      U16 q0,q1,q2,q3;                                                          \
      q0.u = wlds4[MT2_4 + (ct*4+0)*64 + l];                                    \
      q1.u = wlds4[MT2_4 + (ct*4+1)*64 + l];                                    \
      q2.u = wlds4[MT2_4 + (ct*4+2)*64 + l];                                    \
      q3.u = wlds4[MT2_4 + (ct*4+3)*64 + l];                                    \
      f4 X = {0.f,0.f,0.f,0.f};                                                 \
      X = __builtin_amdgcn_mfma_f32_16x16x32_f16(q0.h, h0.h, X, 0, 0, 0);       \
      X = __builtin_amdgcn_mfma_f32_16x16x32_f16(q1.h, h1.h, X, 0, 0, 0);       \
      X = __builtin_amdgcn_mfma_f32_16x16x32_f16(q2.h, h2.h, X, 0, 0, 0);       \
      X = __builtin_amdgcn_mfma_f32_16x16x32_f16(q3.h, h3.h, X, 0, 0, 0);       \
      float4 bb = *(const float4*)&bias_lds[384 + ct*16 + g*4];                 \
      accT[ct].x = phh(X[0]+bb.x, X[1]+bb.y);                                   \
      accT[ct].y = phh(X[2]+bb.z, X[3]+bb.w);                                   \
    }                                                                           \
  }                                                                             \
  /* w-L1 -> hb (mw1 frags from GLOBAL, 16KB L1-resident) */                    \
  _Pragma("unroll")                                                             \
  for (int ct = 0; ct < 8; ct++){                                               \
    U16 q0,q1;                                                                  \
    q0.u = mw1p[(ct*2+0)*64 + l];                                               \
    q1.u = mw1p[(ct*2+1)*64 + l];                                               \
    f4 B = {0.f,0.f,0.f,0.f};                                                   \
    B = __builtin_amdgcn_mfma_f32_16x16x32_f16(q0.h, wf0.h, B, 0, 0, 0);        \
    B = __builtin_amdgcn_mfma_f32_16x16x32_f16(q1.h, wf1.h, B, 0, 0, 0);        \
    float4 bb = *(const float4*)&bias_lds[0 + ct*16 + g*4];                     \
    uint2 v;                                                                    \
    v.x = phh(fmaxf(B[0]+bb.x,0.f), fmaxf(B[1]+bb.y,0.f));                      \
    v.y = phh(fmaxf(B[2]+bb.z,0.f), fmaxf(B[3]+bb.w,0.f));                      \
    *(uint2*)&myhb[e16*128 + ((ct*16 + g*4) ^ swz)] = v;                        \
  }                                                                             \
  /* w-L2 + fused epilogue */                                                   \
  {                                                                             \
    U16 h0,h1,h2,h3;                                                            \
    h0.u = *(const uint4*)&myhb[e16*128 + (( 0 + g*8) ^ swz)];                  \
    h1.u = *(const uint4*)&myhb[e16*128 + ((32 + g*8) ^ swz)];                  \
    h2.u = *(const uint4*)&myhb[e16*128 + ((64 + g*8) ^ swz)];                  \
    h3.u = *(const uint4*)&myhb[e16*128 + ((96 + g*8) ^ swz)];                  \
    _Pragma("unroll")                                                           \
    for (int ct = 0; ct < 8; ct++){                                             \
      U16 q0,q1,q2,q3;                                                          \
      q0.u = wlds4[MW2_4 + (ct*4+0)*64 + l];                                    \
      q1.u = wlds4[MW2_4 + (ct*4+1)*64 + l];                                    \
      q2.u = wlds4[MW2_4 + (ct*4+2)*64 + l];                                    \
      q3.u = wlds4[MW2_4 + (ct*4+3)*64 + l];                                    \
      f4 Y = {0.f,0.f,0.f,0.f};                                                 \
      Y = __builtin_amdgcn_mfma_f32_16x16x32_f16(q0.h, h0.h, Y, 0, 0, 0);       \
      Y = __builtin_amdgcn_mfma_f32_16x16x32_f16(q1.h, h1.h, Y, 0, 0, 0);       \
      Y = __builtin_amdgcn_mfma_f32_16x16x32_f16(q2.h, h2.h, Y, 0, 0, 0);       \
      Y = __builtin_amdgcn_mfma_f32_16x16x32_f16(q3.h, h3.h, Y, 0, 0, 0);       \
      float4 bb = *(const float4*)&bias_lds[128 + ct*16 + g*4];                 \
      float2 tlo = up2(accT[ct].x), thi = up2(accT[ct].y);                      \
      float4 o;                                                                 \
      o.x = (Y[0] + bb.x) * tlo.x;                                              \
      o.y = (Y[1] + bb.y) * tlo.y;                                              \
      o.z = (Y[2] + bb.z) * thi.x;                                              \
      o.w = (Y[3] + bb.w) * thi.y;                                              \
      *(float4*)&out[(size_t)((TIDX)*16 + e16)*128 + ct*16 + g*4] = o;          \
    }                                                                           \
  }                                                                             \
}

__global__ __launch_bounds__(960, 4) void k2_mlp(
    const u16* __restrict__ Q, const u16* __restrict__ Kv,
    const int* __restrict__ eidx, const float* __restrict__ T,
    const u16* __restrict__ wsrc,           // pack + 73728 (mw2,mt1,mt2 linear, 96KB)
    const uint4* __restrict__ mw1p,         // pack + 65536 (mw1, stays global)
    const float* __restrict__ b1w, const float* __restrict__ b2w,
    const float* __restrict__ b1t, const float* __restrict__ b2t,
    float* __restrict__ out, int nTiles)
{
  __shared__ alignas(16) u16   wlds[49152];    // 96KB: mw2 | mt1 | mt2
  __shared__ alignas(16) float bias_lds[512];  // b1w|b2w|b1t|b2t
  __shared__ alignas(16) u16   hb[15][2048];   // 4KB hidden buffer per wave
  {
    const uint4* src = (const uint4*)wsrc;
    uint4* dst = (uint4*)wlds;
    for (int i = threadIdx.x; i < 6144; i += 960)
      dst[i] = src[i];
    int tt = threadIdx.x;
    if (tt < 512){
      float bv = (tt < 128) ? b1w[tt] : (tt < 256) ? b2w[tt-128]
               : (tt < 384) ? b1t[tt-256] : b2t[tt-384];
      bias_lds[tt] = bv;
    }
  }
  __syncthreads();                             // only barrier in the kernel

  const int wv = threadIdx.x >> 6;             // 0..14
  const int l  = threadIdx.x & 63;
  const int e16 = l & 15, g = l >> 4;
  const int swz = (e16 & 7) << 3;
  const uint4* wlds4 = (const uint4*)wlds;
  u16* myhb = hb[wv];
  const int tStride = gridDim.x * 15;

  h8 tA0, tA1, tA2, tA3;
  h8 tB0, tB1, tB2, tB3;
  U16 gq0, gq1, gq2, gq3, gq4, gq5, gq6, gq7;
  U16 gk0, gk1, gk2, gk3, gk4, gk5, gk6, gk7;
  U16 wf0, wf1;

  int t = blockIdx.x*15 + wv;                  // max 3839 < nTiles (20000)
  TLOAD(tA0,tA1,tA2,tA3,t)
  GLOAD(t)
  while (true){
    int tn = t + tStride;
    bool v1 = tn < nTiles;
    DOT2()                                     // tile t's w from G regs (frees G)
    if (v1) { TLOAD(tB0,tB1,tB2,tB3,tn) GLOAD(tn) }
    K2_TILE(tA0,tA1,tA2,tA3,t)                 // gathers for tn land under this
    if (!v1) return;
    int tn2 = tn + tStride;
    bool v2 = tn2 < nTiles;
    DOT2()                                     // tile tn's w
    if (v2) { TLOAD(tA0,tA1,tA2,tA3,tn2) GLOAD(tn2) }
    K2_TILE(tB0,tB1,tB2,tB3,tn)
    if (!v2) return;
    t = tn2;
  }
}

extern "C" void kernel_launch(void* const* d_in, const int* in_sizes, int n_in,
                              void* d_out, int out_size, void* d_ws, size_t ws_size,
                              hipStream_t stream) {
  const float* X   = (const float*)d_in[0];
  const float* T   = (const float*)d_in[1];
  const int*   EI  = (const int*)  d_in[2];
  const float* Wq  = (const float*)d_in[3];
  const float* Wk  = (const float*)d_in[4];
  const float* w1w = (const float*)d_in[5];
  const float* b1w = (const float*)d_in[6];
  const float* w2w = (const float*)d_in[7];
  const float* b2w = (const float*)d_in[8];
  const float* w1t = (const float*)d_in[9];
  const float* b1t = (const float*)d_in[10];
  const float* w2t = (const float*)d_in[11];
  const float* b2t = (const float*)d_in[12];
  float* out = (float*)d_out;

  u16* ws   = (u16*)d_ws;
  u16* pack = ws;                           // 240 KB packed weights
  u16* Q    = ws + 122880;                  // [N][256] f16 (10.24 MB)
  u16* Kv   = Q + (size_t)NN*256;           // [N][256] f16 (10.24 MB)

  k0_pack<<<64, 256, 0, stream>>>(Wq, Wk, w1w, w2w, w1t, w2t, pack);
  k1_proj<<<dim3((NN + 63)/64, 4), 256, 0, stream>>>(X, pack, Q, Kv);
  k2_mlp<<<256, 960, 0, stream>>>(Q, Kv, EI, T,
      (const u16*)(ws + 73728), (const uint4*)(ws + 65536),
      b1w, b2w, b1t, b2t, out, EE/16);
}

// Round 13
// 429.125 us; speedup vs baseline: 1.0059x; 1.0059x over previous
//
#include <hip/hip_runtime.h>

#define NN 20000
#define EE 320000

typedef unsigned int  u32;
typedef unsigned short u16;

typedef _Float16 h8 __attribute__((ext_vector_type(8)));
typedef _Float16 h2 __attribute__((ext_vector_type(2)));
typedef float    f4 __attribute__((ext_vector_type(4)));

union U16 { uint4 u; h8 h; };

__device__ inline u32 phh(float a, float b){
  h2 v; v[0] = (_Float16)a; v[1] = (_Float16)b;
  return __builtin_bit_cast(u32, v);
}
__device__ inline u16 f2h_u(float a){
  _Float16 h = (_Float16)a;
  return __builtin_bit_cast(u16, h);
}
__device__ inline float2 up2(u32 u){
  h2 v = __builtin_bit_cast(h2, u);
  return make_float2((float)v[0], (float)v[1]);
}
__device__ inline h8 pack8(float4 a, float4 b){
  U16 t;
  t.u.x = phh(a.x, a.y);
  t.u.y = phh(a.z, a.w);
  t.u.z = phh(b.x, b.y);
  t.u.w = phh(b.z, b.w);
  return t.h;
}

// ---------------------------------------------------------------------------
// k0: pack all weights into MFMA fragment order, f16.
// Frag layout (16x16x32): lane holds M[k=(lane/16)*8+j][c=ct*16+lane%16].
// ws (u16 units):
//   [0,65536)        W2pack: [d][ct(8)][ks(4)][lane(64)][j(8)]  (c 0-63=Wq, 64-127=Wk[d])
//   [65536,73728)    mw1pack: [ct(8)][ks(2)][lane][j]   (K=64) — stays GLOBAL (L1-hot)
//   [73728,90112)    mw2pack  ┐
//   [90112,106496)   mt1pack  ├ staged into k2's LDS (96KB)
//   [106496,122880)  mt2pack  ┘
// ---------------------------------------------------------------------------
__global__ void k0_pack(const float* __restrict__ Wq, const float* __restrict__ Wk,
                        const float* __restrict__ w1w, const float* __restrict__ w2w,
                        const float* __restrict__ w1t, const float* __restrict__ w2t,
                        u16* __restrict__ pack)
{
  const int tot = 65536 + 8192 + 16384*3;
  for (int o = blockIdx.x*blockDim.x + threadIdx.x; o < tot; o += gridDim.x*blockDim.x){
    float v;
    if (o < 65536){
      int d = o >> 14, r = o & 16383;
      int ct = r >> 11, ks = (r >> 9) & 3, lane = (r >> 3) & 63, j = r & 7;
      int k = ks*32 + (lane >> 4)*8 + j, c = ct*16 + (lane & 15);
      v = (c < 64) ? Wq[k*64 + c] : Wk[((d << 7) + k)*64 + (c - 64)];
    } else if (o < 73728){
      int r = o - 65536;
      int ct = r >> 10, ks = (r >> 9) & 1, lane = (r >> 3) & 63, j = r & 7;
      int k = ks*32 + (lane >> 4)*8 + j, c = ct*16 + (lane & 15);
      v = w1w[k*128 + c];
    } else {
      int r = o - 73728;
      int m = r >> 14; r &= 16383;
      int ct = r >> 11, ks = (r >> 9) & 3, lane = (r >> 3) & 63, j = r & 7;
      int k = ks*32 + (lane >> 4)*8 + j, c = ct*16 + (lane & 15);
      const float* M = (m == 0) ? w2w : (m == 1) ? w1t : w2t;
      v = M[k*128 + c];
    }
    pack[o] = f2h_u(v);
  }
}

// ---------------------------------------------------------------------------
// k1: per-d projection GEMM: [N x 128] @ [128 x 128] -> q||k per node, f16.
// ---------------------------------------------------------------------------
__global__ __launch_bounds__(256) void k1_proj(const float* __restrict__ X,
    const u16* __restrict__ wpack, u16* __restrict__ Q, u16* __restrict__ Kv)
{
  const int d = blockIdx.y;
  const int nBase = blockIdx.x * 64;
  const int wv = threadIdx.x >> 6;
  const int l  = threadIdx.x & 63;
  const int row16 = l & 15, g = l >> 4;
  int node_a = nBase + wv*16 + row16;
  int na = node_a < NN ? node_a : NN-1;          // clamp; stores are guarded
  const float* xrow = X + ((size_t)d*NN + na)*128;
  h8 a[4];
  #pragma unroll
  for (int ks = 0; ks < 4; ks++){
    float4 f0 = *(const float4*)(xrow + ks*32 + g*8);
    float4 f1 = *(const float4*)(xrow + ks*32 + g*8 + 4);
    a[ks] = pack8(f0, f1);
  }
  const uint4* wp4 = (const uint4*)wpack;
  #pragma unroll
  for (int ct = 0; ct < 8; ct++){
    f4 acc = {0.f, 0.f, 0.f, 0.f};
    #pragma unroll
    for (int ks = 0; ks < 4; ks++){
      U16 b; b.u = wp4[((d*8 + ct)*4 + ks)*64 + l];
      acc = __builtin_amdgcn_mfma_f32_16x16x32_f16(a[ks], b.h, acc, 0, 0, 0);
    }
    u16* dst = (ct < 4) ? Q : Kv;
    int cc = (ct & 3)*16 + row16;
    #pragma unroll
    for (int r = 0; r < 4; r++){
      int node = nBase + wv*16 + g*4 + r;        // D: col=lane&15, row=(lane>>4)*4+r
      if (node < NN) dst[(size_t)node*256 + d*64 + cc] = f2h_u(acc[r]);
    }
  }
}

// ---------------------------------------------------------------------------
// k2_mlp v9b: persistent-weights + fused gather/dot, 15-wave occupancy.
//  R13 fix vs R12: __launch_bounds__(960,3) not (960,4). A 15-wave block is
//  3.75 waves/EU; demanding 4 forced the compiler to assume 2 blocks/CU ->
//  VGPR cap 64 -> catastrophic spill (WRITE 582MB). With min=3, one block
//  satisfies the bound and VGPR relaxes to ~128 (R9 compiled this body at 128).
//  LDS: 96KB weights (mw2,mt1,mt2) + 2KB bias + 15x4KB hidden = 158KB.
//  mw1 frags come from global (16KB, L1-resident).
// ---------------------------------------------------------------------------
#define MW2_4 0
#define MT1_4 2048
#define MT2_4 4096

#define TLOAD(TF0,TF1,TF2,TF3,TIDX)                                             \
{                                                                               \
  const float* trow_ = T + (size_t)((TIDX)*16 + e16)*128;                       \
  float4 a_, b_;                                                                \
  a_ = *(const float4*)(trow_ +  0 + g*8); b_ = *(const float4*)(trow_ +  0 + g*8 + 4); TF0 = pack8(a_,b_); \
  a_ = *(const float4*)(trow_ + 32 + g*8); b_ = *(const float4*)(trow_ + 32 + g*8 + 4); TF1 = pack8(a_,b_); \
  a_ = *(const float4*)(trow_ + 64 + g*8); b_ = *(const float4*)(trow_ + 64 + g*8 + 4); TF2 = pack8(a_,b_); \
  a_ = *(const float4*)(trow_ + 96 + g*8); b_ = *(const float4*)(trow_ + 96 + g*8 + 4); TF3 = pack8(a_,b_); \
}

#define GLOAD(TIDX)                                                             \
{                                                                               \
  const int e_ = (TIDX)*16 + e16;                                               \
  const int nj_ = eidx[e_];                                                     \
  const int ni_ = eidx[EE + e_];                                                \
  const u16* qb_ = Q  + ((size_t)ni_ << 8) + g*8;                               \
  const u16* kb_ = Kv + ((size_t)nj_ << 8) + g*8;                               \
  gq0.u = *(const uint4*)(qb_      );  gq1.u = *(const uint4*)(qb_ +  64);      \
  gq2.u = *(const uint4*)(qb_ + 128);  gq3.u = *(const uint4*)(qb_ + 192);      \
  gq4.u = *(const uint4*)(qb_ +  32);  gq5.u = *(const uint4*)(qb_ +  96);      \
  gq6.u = *(const uint4*)(qb_ + 160);  gq7.u = *(const uint4*)(qb_ + 224);      \
  gk0.u = *(const uint4*)(kb_      );  gk1.u = *(const uint4*)(kb_ +  64);      \
  gk2.u = *(const uint4*)(kb_ + 128);  gk3.u = *(const uint4*)(kb_ + 192);      \
  gk4.u = *(const uint4*)(kb_ +  32);  gk5.u = *(const uint4*)(kb_ +  96);      \
  gk6.u = *(const uint4*)(kb_ + 160);  gk7.u = *(const uint4*)(kb_ + 224);      \
}

#define DOT_HALF(Q0,Q1,Q2,Q3,K0,K1,K2,K3,WF)                                    \
{                                                                               \
  float s_[8];                                                                  \
  _Pragma("unroll")                                                             \
  for (int j = 0; j < 8; j++)                                                   \
    s_[j] = (float)Q0.h[j]*(float)K0.h[j] + (float)Q1.h[j]*(float)K1.h[j]       \
          + (float)Q2.h[j]*(float)K2.h[j] + (float)Q3.h[j]*(float)K3.h[j];      \
  U16 t_;                                                                       \
  t_.u.x = phh(s_[0],s_[1]); t_.u.y = phh(s_[2],s_[3]);                         \
  t_.u.z = phh(s_[4],s_[5]); t_.u.w = phh(s_[6],s_[7]);                         \
  WF = t_;                                                                      \
}

#define DOT2()                                                                  \
  DOT_HALF(gq0,gq1,gq2,gq3,gk0,gk1,gk2,gk3,wf0)                                 \
  DOT_HALF(gq4,gq5,gq6,gq7,gk4,gk5,gk6,gk7,wf1)

#define K2_TILE(TF0,TF1,TF2,TF3,TIDX)                                           \
{                                                                               \
  /* t-L1 -> hb */                                                              \
  _Pragma("unroll")                                                             \
  for (int ct = 0; ct < 8; ct++){                                               \
    U16 q0,q1,q2,q3;                                                            \
    q0.u = wlds4[MT1_4 + (ct*4+0)*64 + l];                                      \
    q1.u = wlds4[MT1_4 + (ct*4+1)*64 + l];                                      \
    q2.u = wlds4[MT1_4 + (ct*4+2)*64 + l];                                      \
    q3.u = wlds4[MT1_4 + (ct*4+3)*64 + l];                                      \
    f4 A = {0.f,0.f,0.f,0.f};                                                   \
    A = __builtin_amdgcn_mfma_f32_16x16x32_f16(q0.h, TF0, A, 0, 0, 0);          \
    A = __builtin_amdgcn_mfma_f32_16x16x32_f16(q1.h, TF1, A, 0, 0, 0);          \
    A = __builtin_amdgcn_mfma_f32_16x16x32_f16(q2.h, TF2, A, 0, 0, 0);          \
    A = __builtin_amdgcn_mfma_f32_16x16x32_f16(q3.h, TF3, A, 0, 0, 0);          \
    float4 bb = *(const float4*)&bias_lds[256 + ct*16 + g*4];                   \
    uint2 v;                                                                    \
    v.x = phh(fmaxf(A[0]+bb.x,0.f), fmaxf(A[1]+bb.y,0.f));                      \
    v.y = phh(fmaxf(A[2]+bb.z,0.f), fmaxf(A[3]+bb.w,0.f));                      \
    *(uint2*)&myhb[e16*128 + ((ct*16 + g*4) ^ swz)] = v;                        \
  }                                                                             \
  /* t-L2 -> accT (f16 packed, incl. b2t) */                                    \
  uint2 accT[8];                                                                \
  {                                                                             \
    U16 h0,h1,h2,h3;                                                            \
    h0.u = *(const uint4*)&myhb[e16*128 + (( 0 + g*8) ^ swz)];                  \
    h1.u = *(const uint4*)&myhb[e16*128 + ((32 + g*8) ^ swz)];                  \
    h2.u = *(const uint4*)&myhb[e16*128 + ((64 + g*8) ^ swz)];                  \
    h3.u = *(const uint4*)&myhb[e16*128 + ((96 + g*8) ^ swz)];                  \
    _Pragma("unroll")                                                           \
    for (int ct = 0; ct < 8; ct++){                                             \
      U16 q0,q1,q2,q3;                                                          \
      q0.u = wlds4[MT2_4 + (ct*4+0)*64 + l];                                    \
      q1.u = wlds4[MT2_4 + (ct*4+1)*64 + l];                                    \
      q2.u = wlds4[MT2_4 + (ct*4+2)*64 + l];                                    \
      q3.u = wlds4[MT2_4 + (ct*4+3)*64 + l];                                    \
      f4 X = {0.f,0.f,0.f,0.f};                                                 \
      X = __builtin_amdgcn_mfma_f32_16x16x32_f16(q0.h, h0.h, X, 0, 0, 0);       \
      X = __builtin_amdgcn_mfma_f32_16x16x32_f16(q1.h, h1.h, X, 0, 0, 0);       \
      X = __builtin_amdgcn_mfma_f32_16x16x32_f16(q2.h, h2.h, X, 0, 0, 0);       \
      X = __builtin_amdgcn_mfma_f32_16x16x32_f16(q3.h, h3.h, X, 0, 0, 0);       \
      float4 bb = *(const float4*)&bias_lds[384 + ct*16 + g*4];                 \
      accT[ct].x = phh(X[0]+bb.x, X[1]+bb.y);                                   \
      accT[ct].y = phh(X[2]+bb.z, X[3]+bb.w);                                   \
    }                                                                           \
  }                                                                             \
  /* w-L1 -> hb (mw1 frags from GLOBAL, 16KB L1-resident) */                    \
  _Pragma("unroll")                                                             \
  for (int ct = 0; ct < 8; ct++){                                               \
    U16 q0,q1;                                                                  \
    q0.u = mw1p[(ct*2+0)*64 + l];                                               \
    q1.u = mw1p[(ct*2+1)*64 + l];                                               \
    f4 B = {0.f,0.f,0.f,0.f};                                                   \
    B = __builtin_amdgcn_mfma_f32_16x16x32_f16(q0.h, wf0.h, B, 0, 0, 0);        \
    B = __builtin_amdgcn_mfma_f32_16x16x32_f16(q1.h, wf1.h, B, 0, 0, 0);        \
    float4 bb = *(const float4*)&bias_lds[0 + ct*16 + g*4];                     \
    uint2 v;                                                                    \
    v.x = phh(fmaxf(B[0]+bb.x,0.f), fmaxf(B[1]+bb.y,0.f));                      \
    v.y = phh(fmaxf(B[2]+bb.z,0.f), fmaxf(B[3]+bb.w,0.f));                      \
    *(uint2*)&myhb[e16*128 + ((ct*16 + g*4) ^ swz)] = v;                        \
  }                                                                             \
  /* w-L2 + fused epilogue */                                                   \
  {                                                                             \
    U16 h0,h1,h2,h3;                                                            \
    h0.u = *(const uint4*)&myhb[e16*128 + (( 0 + g*8) ^ swz)];                  \
    h1.u = *(const uint4*)&myhb[e16*128 + ((32 + g*8) ^ swz)];                  \
    h2.u = *(const uint4*)&myhb[e16*128 + ((64 + g*8) ^ swz)];                  \
    h3.u = *(const uint4*)&myhb[e16*128 + ((96 + g*8) ^ swz)];                  \
    _Pragma("unroll")                                                           \
    for (int ct = 0; ct < 8; ct++){                                             \
      U16 q0,q1,q2,q3;                                                          \
      q0.u = wlds4[MW2_4 + (ct*4+0)*64 + l];                                    \
      q1.u = wlds4[MW2_4 + (ct*4+1)*64 + l];                                    \
      q2.u = wlds4[MW2_4 + (ct*4+2)*64 + l];                                    \
      q3.u = wlds4[MW2_4 + (ct*4+3)*64 + l];                                    \
      f4 Y = {0.f,0.f,0.f,0.f};                                                 \
      Y = __builtin_amdgcn_mfma_f32_16x16x32_f16(q0.h, h0.h, Y, 0, 0, 0);       \
      Y = __builtin_amdgcn_mfma_f32_16x16x32_f16(q1.h, h1.h, Y, 0, 0, 0);       \
      Y = __builtin_amdgcn_mfma_f32_16x16x32_f16(q2.h, h2.h, Y, 0, 0, 0);       \
      Y = __builtin_amdgcn_mfma_f32_16x16x32_f16(q3.h, h3.h, Y, 0, 0, 0);       \
      float4 bb = *(const float4*)&bias_lds[128 + ct*16 + g*4];                 \
      float2 tlo = up2(accT[ct].x), thi = up2(accT[ct].y);                      \
      float4 o;                                                                 \
      o.x = (Y[0] + bb.x) * tlo.x;                                              \
      o.y = (Y[1] + bb.y) * tlo.y;                                              \
      o.z = (Y[2] + bb.z) * thi.x;                                              \
      o.w = (Y[3] + bb.w) * thi.y;                                              \
      *(float4*)&out[(size_t)((TIDX)*16 + e16)*128 + ct*16 + g*4] = o;          \
    }                                                                           \
  }                                                                             \
}

__global__ __launch_bounds__(960, 3) void k2_mlp(
    const u16* __restrict__ Q, const u16* __restrict__ Kv,
    const int* __restrict__ eidx, const float* __restrict__ T,
    const u16* __restrict__ wsrc,           // pack + 73728 (mw2,mt1,mt2 linear, 96KB)
    const uint4* __restrict__ mw1p,         // pack + 65536 (mw1, stays global)
    const float* __restrict__ b1w, const float* __restrict__ b2w,
    const float* __restrict__ b1t, const float* __restrict__ b2t,
    float* __restrict__ out, int nTiles)
{
  __shared__ alignas(16) u16   wlds[49152];    // 96KB: mw2 | mt1 | mt2
  __shared__ alignas(16) float bias_lds[512];  // b1w|b2w|b1t|b2t
  __shared__ alignas(16) u16   hb[15][2048];   // 4KB hidden buffer per wave
  {
    const uint4* src = (const uint4*)wsrc;
    uint4* dst = (uint4*)wlds;
    for (int i = threadIdx.x; i < 6144; i += 960)
      dst[i] = src[i];
    int tt = threadIdx.x;
    if (tt < 512){
      float bv = (tt < 128) ? b1w[tt] : (tt < 256) ? b2w[tt-128]
               : (tt < 384) ? b1t[tt-256] : b2t[tt-384];
      bias_lds[tt] = bv;
    }
  }
  __syncthreads();                             // only barrier in the kernel

  const int wv = threadIdx.x >> 6;             // 0..14
  const int l  = threadIdx.x & 63;
  const int e16 = l & 15, g = l >> 4;
  const int swz = (e16 & 7) << 3;
  const uint4* wlds4 = (const uint4*)wlds;
  u16* myhb = hb[wv];
  const int tStride = gridDim.x * 15;

  h8 tA0, tA1, tA2, tA3;
  h8 tB0, tB1, tB2, tB3;
  U16 gq0, gq1, gq2, gq3, gq4, gq5, gq6, gq7;
  U16 gk0, gk1, gk2, gk3, gk4, gk5, gk6, gk7;
  U16 wf0, wf1;

  int t = blockIdx.x*15 + wv;                  // max 3839 < nTiles (20000)
  TLOAD(tA0,tA1,tA2,tA3,t)
  GLOAD(t)
  while (true){
    int tn = t + tStride;
    bool v1 = tn < nTiles;
    DOT2()                                     // tile t's w from G regs (frees G)
    if (v1) { TLOAD(tB0,tB1,tB2,tB3,tn) GLOAD(tn) }
    K2_TILE(tA0,tA1,tA2,tA3,t)                 // gathers for tn land under this
    if (!v1) return;
    int tn2 = tn + tStride;
    bool v2 = tn2 < nTiles;
    DOT2()                                     // tile tn's w
    if (v2) { TLOAD(tA0,tA1,tA2,tA3,tn2) GLOAD(tn2) }
    K2_TILE(tB0,tB1,tB2,tB3,tn)
    if (!v2) return;
    t = tn2;
  }
}

extern "C" void kernel_launch(void* const* d_in, const int* in_sizes, int n_in,
                              void* d_out, int out_size, void* d_ws, size_t ws_size,
                              hipStream_t stream) {
  const float* X   = (const float*)d_in[0];
  const float* T   = (const float*)d_in[1];
  const int*   EI  = (const int*)  d_in[2];
  const float* Wq  = (const float*)d_in[3];
  const float* Wk  = (const float*)d_in[4];
  const float* w1w = (const float*)d_in[5];
  const float* b1w = (const float*)d_in[6];
  const float* w2w = (const float*)d_in[7];
  const float* b2w = (const float*)d_in[8];
  const float* w1t = (const float*)d_in[9];
  const float* b1t = (const float*)d_in[10];
  const float* w2t = (const float*)d_in[11];
  const float* b2t = (const float*)d_in[12];
  float* out = (float*)d_out;

  u16* ws   = (u16*)d_ws;
  u16* pack = ws;                           // 240 KB packed weights
  u16* Q    = ws + 122880;                  // [N][256] f16 (10.24 MB)
  u16* Kv   = Q + (size_t)NN*256;           // [N][256] f16 (10.24 MB)

  k0_pack<<<64, 256, 0, stream>>>(Wq, Wk, w1w, w2w, w1t, w2t, pack);
  k1_proj<<<dim3((NN + 63)/64, 4), 256, 0, stream>>>(X, pack, Q, Kv);
  k2_mlp<<<256, 960, 0, stream>>>(Q, Kv, EI, T,
      (const u16*)(ws + 73728), (const uint4*)(ws + 65536),
      b1w, b2w, b1t, b2t, out, EE/16);
}

// Round 14
// 267.497 us; speedup vs baseline: 1.6137x; 1.6042x over previous
//
#include <hip/hip_runtime.h>

#define NN 20000
#define EE 320000

typedef unsigned int  u32;
typedef unsigned short u16;

typedef _Float16 h8 __attribute__((ext_vector_type(8)));
typedef _Float16 h2 __attribute__((ext_vector_type(2)));
typedef float    f4 __attribute__((ext_vector_type(4)));

union U16 { uint4 u; h8 h; };

__device__ inline u32 phh(float a, float b){
  h2 v; v[0] = (_Float16)a; v[1] = (_Float16)b;
  return __builtin_bit_cast(u32, v);
}
__device__ inline u16 f2h_u(float a){
  _Float16 h = (_Float16)a;
  return __builtin_bit_cast(u16, h);
}
__device__ inline float2 up2(u32 u){
  h2 v = __builtin_bit_cast(h2, u);
  return make_float2((float)v[0], (float)v[1]);
}
__device__ inline h8 pack8(float4 a, float4 b){
  U16 t;
  t.u.x = phh(a.x, a.y);
  t.u.y = phh(a.z, a.w);
  t.u.z = phh(b.x, b.y);
  t.u.w = phh(b.z, b.w);
  return t.h;
}

// ---------------------------------------------------------------------------
// k0: pack all weights into MFMA fragment order, f16.
// Frag layout (16x16x32): lane holds M[k=(lane/16)*8+j][c=ct*16+lane%16].
// ws (u16 units):
//   [0,65536)        W2pack: [d][ct(8)][ks(4)][lane(64)][j(8)]  (c 0-63=Wq, 64-127=Wk[d])
//   [65536,73728)    mw1pack — stays GLOBAL in k2 (16KB, L1/L2-hot)
//   [73728,90112)    mw2pack  ┐
//   [90112,106496)   mt1pack  ├ staged into k2's LDS (96KB)
//   [106496,122880)  mt2pack  ┘
// ---------------------------------------------------------------------------
__global__ void k0_pack(const float* __restrict__ Wq, const float* __restrict__ Wk,
                        const float* __restrict__ w1w, const float* __restrict__ w2w,
                        const float* __restrict__ w1t, const float* __restrict__ w2t,
                        u16* __restrict__ pack)
{
  const int tot = 65536 + 8192 + 16384*3;
  for (int o = blockIdx.x*blockDim.x + threadIdx.x; o < tot; o += gridDim.x*blockDim.x){
    float v;
    if (o < 65536){
      int d = o >> 14, r = o & 16383;
      int ct = r >> 11, ks = (r >> 9) & 3, lane = (r >> 3) & 63, j = r & 7;
      int k = ks*32 + (lane >> 4)*8 + j, c = ct*16 + (lane & 15);
      v = (c < 64) ? Wq[k*64 + c] : Wk[((d << 7) + k)*64 + (c - 64)];
    } else if (o < 73728){
      int r = o - 65536;
      int ct = r >> 10, ks = (r >> 9) & 1, lane = (r >> 3) & 63, j = r & 7;
      int k = ks*32 + (lane >> 4)*8 + j, c = ct*16 + (lane & 15);
      v = w1w[k*128 + c];
    } else {
      int r = o - 73728;
      int m = r >> 14; r &= 16383;
      int ct = r >> 11, ks = (r >> 9) & 3, lane = (r >> 3) & 63, j = r & 7;
      int k = ks*32 + (lane >> 4)*8 + j, c = ct*16 + (lane & 15);
      const float* M = (m == 0) ? w2w : (m == 1) ? w1t : w2t;
      v = M[k*128 + c];
    }
    pack[o] = f2h_u(v);
  }
}

// ---------------------------------------------------------------------------
// k1: per-d projection GEMM: [N x 128] @ [128 x 128] -> q||k per node, f16.
// ---------------------------------------------------------------------------
__global__ __launch_bounds__(256) void k1_proj(const float* __restrict__ X,
    const u16* __restrict__ wpack, u16* __restrict__ Q, u16* __restrict__ Kv)
{
  const int d = blockIdx.y;
  const int nBase = blockIdx.x * 64;
  const int wv = threadIdx.x >> 6;
  const int l  = threadIdx.x & 63;
  const int row16 = l & 15, g = l >> 4;
  int node_a = nBase + wv*16 + row16;
  int na = node_a < NN ? node_a : NN-1;          // clamp; stores are guarded
  const float* xrow = X + ((size_t)d*NN + na)*128;
  h8 a[4];
  #pragma unroll
  for (int ks = 0; ks < 4; ks++){
    float4 f0 = *(const float4*)(xrow + ks*32 + g*8);
    float4 f1 = *(const float4*)(xrow + ks*32 + g*8 + 4);
    a[ks] = pack8(f0, f1);
  }
  const uint4* wp4 = (const uint4*)wpack;
  #pragma unroll
  for (int ct = 0; ct < 8; ct++){
    f4 acc = {0.f, 0.f, 0.f, 0.f};
    #pragma unroll
    for (int ks = 0; ks < 4; ks++){
      U16 b; b.u = wp4[((d*8 + ct)*4 + ks)*64 + l];
      acc = __builtin_amdgcn_mfma_f32_16x16x32_f16(a[ks], b.h, acc, 0, 0, 0);
    }
    u16* dst = (ct < 4) ? Q : Kv;
    int cc = (ct & 3)*16 + row16;
    #pragma unroll
    for (int r = 0; r < 4; r++){
      int node = nBase + wv*16 + g*4 + r;        // D: col=lane&15, row=(lane>>4)*4+r
      if (node < NN) dst[(size_t)node*256 + d*64 + cc] = f2h_u(acc[r]);
    }
  }
}

// ---------------------------------------------------------------------------
// kA: gather + edge dot -> w_ij f16 [E][64] in ws. (R8-validated)
// ---------------------------------------------------------------------------
__global__ __launch_bounds__(256) void kA_dot(
    const u16* __restrict__ Q, const u16* __restrict__ Kv,
    const int* __restrict__ eidx, u16* __restrict__ Wg)
{
  const int wv = threadIdx.x >> 6;
  const int l  = threadIdx.x & 63;
  const int eBase = (blockIdx.x*4 + wv)*16;
  const int er = l >> 2, p = l & 3;
  const int eg = eBase + er;
  const int nj = eidx[eg];        // edge_index[0] = n_j (sender, uses ek)
  const int ni = eidx[EE + eg];   // edge_index[1] = n_i (receiver, uses eq)
  const u16* qb = Q  + (size_t)ni*256 + p*16;
  const u16* kb = Kv + (size_t)nj*256 + p*16;
  float acc16[16];
  #pragma unroll
  for (int j = 0; j < 16; j++) acc16[j] = 0.f;
  #pragma unroll
  for (int dd = 0; dd < 4; dd++){
    uint4 qa = *(const uint4*)(qb + dd*64);
    uint4 qc = *(const uint4*)(qb + dd*64 + 8);
    uint4 ka = *(const uint4*)(kb + dd*64);
    uint4 kc = *(const uint4*)(kb + dd*64 + 8);
    u32 qs[8] = {qa.x,qa.y,qa.z,qa.w,qc.x,qc.y,qc.z,qc.w};
    u32 ks_[8] = {ka.x,ka.y,ka.z,ka.w,kc.x,kc.y,kc.z,kc.w};
    #pragma unroll
    for (int j = 0; j < 8; j++){
      float2 qf = up2(qs[j]), kf = up2(ks_[j]);
      acc16[2*j]   += qf.x * kf.x;
      acc16[2*j+1] += qf.y * kf.y;
    }
  }
  uint4 wlo, whi;
  wlo.x = phh(acc16[0],acc16[1]);   wlo.y = phh(acc16[2],acc16[3]);
  wlo.z = phh(acc16[4],acc16[5]);   wlo.w = phh(acc16[6],acc16[7]);
  whi.x = phh(acc16[8],acc16[9]);   whi.y = phh(acc16[10],acc16[11]);
  whi.z = phh(acc16[12],acc16[13]); whi.w = phh(acc16[14],acc16[15]);
  uint4* dst = (uint4*)(Wg + (size_t)eg*64 + p*16);
  dst[0] = wlo;
  dst[1] = whi;
}

// ---------------------------------------------------------------------------
// k2_mlp v10: R8 persistent-weights base + 12-wave block.
//  - 768 threads (12 waves), launch_bounds(768,1): block-fit constraint caps
//    VGPR at ~170 (12 waves = 3/SIMD); avoids the >8-wave + min-waves>=2
//    heuristic that clamped VGPR to 64 (R12/R13)
//  - mw1 (16KB) from GLOBAL (L1/L2-hot, 16 loads/tile amortized over 16 MFMAs)
//  - LDS: 96KB weights (mw2,mt1,mt2) + 2KB bias + 12x4KB hidden = 146KB
//  - otherwise identical to R8 (passed, k2=91us): Wg from kA, named-reg
//    prefetch ping-pong, hidden buffer reused t-chain -> w-chain
// ---------------------------------------------------------------------------
#define MW2_4 0
#define MT1_4 2048
#define MT2_4 4096

#define K2_LOAD(TF0,TF1,TF2,TF3,WF0,WF1,TIDX)                                   \
{                                                                               \
  const int e_ = (TIDX)*16 + e16;                                               \
  const float* trow_ = T + (size_t)e_*128;                                      \
  float4 a_, b_;                                                                \
  a_ = *(const float4*)(trow_ +  0 + g*8); b_ = *(const float4*)(trow_ +  0 + g*8 + 4); TF0 = pack8(a_,b_); \
  a_ = *(const float4*)(trow_ + 32 + g*8); b_ = *(const float4*)(trow_ + 32 + g*8 + 4); TF1 = pack8(a_,b_); \
  a_ = *(const float4*)(trow_ + 64 + g*8); b_ = *(const float4*)(trow_ + 64 + g*8 + 4); TF2 = pack8(a_,b_); \
  a_ = *(const float4*)(trow_ + 96 + g*8); b_ = *(const float4*)(trow_ + 96 + g*8 + 4); TF3 = pack8(a_,b_); \
  const uint4* wrow_ = (const uint4*)(Wg + (size_t)e_*64);                      \
  WF0.u = wrow_[g];                                                             \
  WF1.u = wrow_[4 + g];                                                         \
}

#define K2_TILE(TF0,TF1,TF2,TF3,WF0,WF1,TIDX)                                   \
{                                                                               \
  /* t-L1 -> hb */                                                              \
  _Pragma("unroll")                                                             \
  for (int ct = 0; ct < 8; ct++){                                               \
    U16 q0,q1,q2,q3;                                                            \
    q0.u = wlds4[MT1_4 + (ct*4+0)*64 + l];                                      \
    q1.u = wlds4[MT1_4 + (ct*4+1)*64 + l];                                      \
    q2.u = wlds4[MT1_4 + (ct*4+2)*64 + l];                                      \
    q3.u = wlds4[MT1_4 + (ct*4+3)*64 + l];                                      \
    f4 A = {0.f,0.f,0.f,0.f};                                                   \
    A = __builtin_amdgcn_mfma_f32_16x16x32_f16(q0.h, TF0, A, 0, 0, 0);          \
    A = __builtin_amdgcn_mfma_f32_16x16x32_f16(q1.h, TF1, A, 0, 0, 0);          \
    A = __builtin_amdgcn_mfma_f32_16x16x32_f16(q2.h, TF2, A, 0, 0, 0);          \
    A = __builtin_amdgcn_mfma_f32_16x16x32_f16(q3.h, TF3, A, 0, 0, 0);          \
    float4 bb = *(const float4*)&bias_lds[256 + ct*16 + g*4];                   \
    uint2 v;                                                                    \
    v.x = phh(fmaxf(A[0]+bb.x,0.f), fmaxf(A[1]+bb.y,0.f));                      \
    v.y = phh(fmaxf(A[2]+bb.z,0.f), fmaxf(A[3]+bb.w,0.f));                      \
    *(uint2*)&myhb[e16*128 + ((ct*16 + g*4) ^ swz)] = v;                        \
  }                                                                             \
  /* t-L2 -> accT (f16 packed, incl. b2t) */                                    \
  uint2 accT[8];                                                                \
  {                                                                             \
    U16 h0,h1,h2,h3;                                                            \
    h0.u = *(const uint4*)&myhb[e16*128 + (( 0 + g*8) ^ swz)];                  \
    h1.u = *(const uint4*)&myhb[e16*128 + ((32 + g*8) ^ swz)];                  \
    h2.u = *(const uint4*)&myhb[e16*128 + ((64 + g*8) ^ swz)];                  \
    h3.u = *(const uint4*)&myhb[e16*128 + ((96 + g*8) ^ swz)];                  \
    _Pragma("unroll")                                                           \
    for (int ct = 0; ct < 8; ct++){                                             \
      U16 q0,q1,q2,q3;                                                          \
      q0.u = wlds4[MT2_4 + (ct*4+0)*64 + l];                                    \
      q1.u = wlds4[MT2_4 + (ct*4+1)*64 + l];                                    \
      q2.u = wlds4[MT2_4 + (ct*4+2)*64 + l];                                    \
      q3.u = wlds4[MT2_4 + (ct*4+3)*64 + l];                                    \
      f4 X = {0.f,0.f,0.f,0.f};                                                 \
      X = __builtin_amdgcn_mfma_f32_16x16x32_f16(q0.h, h0.h, X, 0, 0, 0);       \
      X = __builtin_amdgcn_mfma_f32_16x16x32_f16(q1.h, h1.h, X, 0, 0, 0);       \
      X = __builtin_amdgcn_mfma_f32_16x16x32_f16(q2.h, h2.h, X, 0, 0, 0);       \
      X = __builtin_amdgcn_mfma_f32_16x16x32_f16(q3.h, h3.h, X, 0, 0, 0);       \
      float4 bb = *(const float4*)&bias_lds[384 + ct*16 + g*4];                 \
      accT[ct].x = phh(X[0]+bb.x, X[1]+bb.y);                                   \
      accT[ct].y = phh(X[2]+bb.z, X[3]+bb.w);                                   \
    }                                                                           \
  }                                                                             \
  /* w-L1 -> hb (mw1 frags from GLOBAL; reuse hb: same-wave DS in-order) */     \
  _Pragma("unroll")                                                             \
  for (int ct = 0; ct < 8; ct++){                                               \
    U16 q0,q1;                                                                  \
    q0.u = mw1p[(ct*2+0)*64 + l];                                               \
    q1.u = mw1p[(ct*2+1)*64 + l];                                               \
    f4 B = {0.f,0.f,0.f,0.f};                                                   \
    B = __builtin_amdgcn_mfma_f32_16x16x32_f16(q0.h, WF0.h, B, 0, 0, 0);        \
    B = __builtin_amdgcn_mfma_f32_16x16x32_f16(q1.h, WF1.h, B, 0, 0, 0);        \
    float4 bb = *(const float4*)&bias_lds[0 + ct*16 + g*4];                     \
    uint2 v;                                                                    \
    v.x = phh(fmaxf(B[0]+bb.x,0.f), fmaxf(B[1]+bb.y,0.f));                      \
    v.y = phh(fmaxf(B[2]+bb.z,0.f), fmaxf(B[3]+bb.w,0.f));                      \
    *(uint2*)&myhb[e16*128 + ((ct*16 + g*4) ^ swz)] = v;                        \
  }                                                                             \
  /* w-L2 + fused epilogue */                                                   \
  {                                                                             \
    U16 h0,h1,h2,h3;                                                            \
    h0.u = *(const uint4*)&myhb[e16*128 + (( 0 + g*8) ^ swz)];                  \
    h1.u = *(const uint4*)&myhb[e16*128 + ((32 + g*8) ^ swz)];                  \
    h2.u = *(const uint4*)&myhb[e16*128 + ((64 + g*8) ^ swz)];                  \
    h3.u = *(const uint4*)&myhb[e16*128 + ((96 + g*8) ^ swz)];                  \
    _Pragma("unroll")                                                           \
    for (int ct = 0; ct < 8; ct++){                                             \
      U16 q0,q1,q2,q3;                                                          \
      q0.u = wlds4[MW2_4 + (ct*4+0)*64 + l];                                    \
      q1.u = wlds4[MW2_4 + (ct*4+1)*64 + l];                                    \
      q2.u = wlds4[MW2_4 + (ct*4+2)*64 + l];                                    \
      q3.u = wlds4[MW2_4 + (ct*4+3)*64 + l];                                    \
      f4 Y = {0.f,0.f,0.f,0.f};                                                 \
      Y = __builtin_amdgcn_mfma_f32_16x16x32_f16(q0.h, h0.h, Y, 0, 0, 0);       \
      Y = __builtin_amdgcn_mfma_f32_16x16x32_f16(q1.h, h1.h, Y, 0, 0, 0);       \
      Y = __builtin_amdgcn_mfma_f32_16x16x32_f16(q2.h, h2.h, Y, 0, 0, 0);       \
      Y = __builtin_amdgcn_mfma_f32_16x16x32_f16(q3.h, h3.h, Y, 0, 0, 0);       \
      float4 bb = *(const float4*)&bias_lds[128 + ct*16 + g*4];                 \
      float2 tlo = up2(accT[ct].x), thi = up2(accT[ct].y);                      \
      float4 o;                                                                 \
      o.x = (Y[0] + bb.x) * tlo.x;                                              \
      o.y = (Y[1] + bb.y) * tlo.y;                                              \
      o.z = (Y[2] + bb.z) * thi.x;                                              \
      o.w = (Y[3] + bb.w) * thi.y;                                              \
      *(float4*)&out[(size_t)((TIDX)*16 + e16)*128 + ct*16 + g*4] = o;          \
    }                                                                           \
  }                                                                             \
}

__global__ __launch_bounds__(768, 1) void k2_mlp(
    const u16* __restrict__ Wg, const float* __restrict__ T,
    const u16* __restrict__ wsrc,           // pack + 73728 (mw2,mt1,mt2, 96KB)
    const uint4* __restrict__ mw1p,         // pack + 65536 (mw1, global)
    const float* __restrict__ b1w, const float* __restrict__ b2w,
    const float* __restrict__ b1t, const float* __restrict__ b2t,
    float* __restrict__ out, int nTiles)
{
  __shared__ alignas(16) u16   wlds[49152];    // 96KB: mw2 | mt1 | mt2
  __shared__ alignas(16) float bias_lds[512];  // b1w|b2w|b1t|b2t
  __shared__ alignas(16) u16   hb[12][2048];   // 4KB hidden buffer per wave
  {
    const uint4* src = (const uint4*)wsrc;
    uint4* dst = (uint4*)wlds;
    for (int i = threadIdx.x; i < 6144; i += 768)
      dst[i] = src[i];
    int tt = threadIdx.x;
    if (tt < 512){
      float bv = (tt < 128) ? b1w[tt] : (tt < 256) ? b2w[tt-128]
               : (tt < 384) ? b1t[tt-256] : b2t[tt-384];
      bias_lds[tt] = bv;
    }
  }
  __syncthreads();                             // only barrier in the kernel

  const int wv = threadIdx.x >> 6;             // 0..11
  const int l  = threadIdx.x & 63;
  const int e16 = l & 15, g = l >> 4;
  const int swz = (e16 & 7) << 3;
  const uint4* wlds4 = (const uint4*)wlds;
  u16* myhb = hb[wv];
  const int tStride = gridDim.x * 12;

  h8 tA0, tA1, tA2, tA3;  U16 wA0, wA1;
  h8 tB0, tB1, tB2, tB3;  U16 wB0, wB1;

  int t = blockIdx.x*12 + wv;                  // max 3071 < nTiles (20000)
  K2_LOAD(tA0,tA1,tA2,tA3,wA0,wA1,t)
  while (true){
    int tn = t + tStride;
    bool v1 = tn < nTiles;
    if (v1) { K2_LOAD(tB0,tB1,tB2,tB3,wB0,wB1,tn) }
    K2_TILE(tA0,tA1,tA2,tA3,wA0,wA1,t)
    if (!v1) return;
    int tn2 = tn + tStride;
    bool v2 = tn2 < nTiles;
    if (v2) { K2_LOAD(tA0,tA1,tA2,tA3,wA0,wA1,tn2) }
    K2_TILE(tB0,tB1,tB2,tB3,wB0,wB1,tn)
    if (!v2) return;
    t = tn2;
  }
}

extern "C" void kernel_launch(void* const* d_in, const int* in_sizes, int n_in,
                              void* d_out, int out_size, void* d_ws, size_t ws_size,
                              hipStream_t stream) {
  const float* X   = (const float*)d_in[0];
  const float* T   = (const float*)d_in[1];
  const int*   EI  = (const int*)  d_in[2];
  const float* Wq  = (const float*)d_in[3];
  const float* Wk  = (const float*)d_in[4];
  const float* w1w = (const float*)d_in[5];
  const float* b1w = (const float*)d_in[6];
  const float* w2w = (const float*)d_in[7];
  const float* b2w = (const float*)d_in[8];
  const float* w1t = (const float*)d_in[9];
  const float* b1t = (const float*)d_in[10];
  const float* w2t = (const float*)d_in[11];
  const float* b2t = (const float*)d_in[12];
  float* out = (float*)d_out;

  u16* ws   = (u16*)d_ws;
  u16* pack = ws;                           // 240 KB packed weights
  u16* Q    = ws + 122880;                  // [N][256] f16 (10.24 MB)
  u16* Kv   = Q + (size_t)NN*256;           // [N][256] f16 (10.24 MB)
  u16* Wg   = Kv + (size_t)NN*256;          // [E][64] f16  (40.96 MB)

  k0_pack<<<64, 256, 0, stream>>>(Wq, Wk, w1w, w2w, w1t, w2t, pack);
  k1_proj<<<dim3((NN + 63)/64, 4), 256, 0, stream>>>(X, pack, Q, Kv);
  kA_dot<<<EE/64, 256, 0, stream>>>(Q, Kv, EI, Wg);
  k2_mlp<<<256, 768, 0, stream>>>(Wg, T,
      (const u16*)(ws + 73728), (const uint4*)(ws + 65536),
      b1w, b2w, b1t, b2t, out, EE/16);
}

// Round 15
// 145.368 us; speedup vs baseline: 2.9694x; 1.8401x over previous
//
#include <hip/hip_runtime.h>

#define NN 20000
#define EE 320000

typedef unsigned int  u32;
typedef unsigned short u16;

typedef _Float16 h8 __attribute__((ext_vector_type(8)));
typedef _Float16 h2 __attribute__((ext_vector_type(2)));
typedef float    f4 __attribute__((ext_vector_type(4)));

union U16 { uint4 u; h8 h; };

__device__ inline u32 phh(float a, float b){
  h2 v; v[0] = (_Float16)a; v[1] = (_Float16)b;
  return __builtin_bit_cast(u32, v);
}
__device__ inline u16 f2h_u(float a){
  _Float16 h = (_Float16)a;
  return __builtin_bit_cast(u16, h);
}
__device__ inline float2 up2(u32 u){
  h2 v = __builtin_bit_cast(h2, u);
  return make_float2((float)v[0], (float)v[1]);
}
__device__ inline h8 pack8(float4 a, float4 b){
  U16 t;
  t.u.x = phh(a.x, a.y);
  t.u.y = phh(a.z, a.w);
  t.u.z = phh(b.x, b.y);
  t.u.w = phh(b.z, b.w);
  return t.h;
}

// ---------------------------------------------------------------------------
// k0: pack all weights into MFMA fragment order, f16.
// Frag layout (16x16x32): lane holds M[k=(lane/16)*8+j][c=ct*16+lane%16].
// ws (u16 units):
//   [0,65536)        W2pack: [d][ct(8)][ks(4)][lane(64)][j(8)]  (c 0-63=Wq, 64-127=Wk[d])
//   [65536,73728)    mw1pack: [ct(8)][ks(2)][lane][j]   (K=64)
//   [73728,90112)    mw2pack
//   [90112,106496)   mt1pack
//   [106496,122880)  mt2pack
// ---------------------------------------------------------------------------
__global__ void k0_pack(const float* __restrict__ Wq, const float* __restrict__ Wk,
                        const float* __restrict__ w1w, const float* __restrict__ w2w,
                        const float* __restrict__ w1t, const float* __restrict__ w2t,
                        u16* __restrict__ pack)
{
  const int tot = 65536 + 8192 + 16384*3;
  for (int o = blockIdx.x*blockDim.x + threadIdx.x; o < tot; o += gridDim.x*blockDim.x){
    float v;
    if (o < 65536){
      int d = o >> 14, r = o & 16383;
      int ct = r >> 11, ks = (r >> 9) & 3, lane = (r >> 3) & 63, j = r & 7;
      int k = ks*32 + (lane >> 4)*8 + j, c = ct*16 + (lane & 15);
      v = (c < 64) ? Wq[k*64 + c] : Wk[((d << 7) + k)*64 + (c - 64)];
    } else if (o < 73728){
      int r = o - 65536;
      int ct = r >> 10, ks = (r >> 9) & 1, lane = (r >> 3) & 63, j = r & 7;
      int k = ks*32 + (lane >> 4)*8 + j, c = ct*16 + (lane & 15);
      v = w1w[k*128 + c];
    } else {
      int r = o - 73728;
      int m = r >> 14; r &= 16383;
      int ct = r >> 11, ks = (r >> 9) & 3, lane = (r >> 3) & 63, j = r & 7;
      int k = ks*32 + (lane >> 4)*8 + j, c = ct*16 + (lane & 15);
      const float* M = (m == 0) ? w2w : (m == 1) ? w1t : w2t;
      v = M[k*128 + c];
    }
    pack[o] = f2h_u(v);
  }
}

// ---------------------------------------------------------------------------
// k1: per-d projection GEMM: [N x 128] @ [128 x 128] -> q||k per node, f16.
// ---------------------------------------------------------------------------
__global__ __launch_bounds__(256) void k1_proj(const float* __restrict__ X,
    const u16* __restrict__ wpack, u16* __restrict__ Q, u16* __restrict__ Kv)
{
  const int d = blockIdx.y;
  const int nBase = blockIdx.x * 64;
  const int wv = threadIdx.x >> 6;
  const int l  = threadIdx.x & 63;
  const int row16 = l & 15, g = l >> 4;
  int node_a = nBase + wv*16 + row16;
  int na = node_a < NN ? node_a : NN-1;          // clamp; stores are guarded
  const float* xrow = X + ((size_t)d*NN + na)*128;
  h8 a[4];
  #pragma unroll
  for (int ks = 0; ks < 4; ks++){
    float4 f0 = *(const float4*)(xrow + ks*32 + g*8);
    float4 f1 = *(const float4*)(xrow + ks*32 + g*8 + 4);
    a[ks] = pack8(f0, f1);
  }
  const uint4* wp4 = (const uint4*)wpack;
  #pragma unroll
  for (int ct = 0; ct < 8; ct++){
    f4 acc = {0.f, 0.f, 0.f, 0.f};
    #pragma unroll
    for (int ks = 0; ks < 4; ks++){
      U16 b; b.u = wp4[((d*8 + ct)*4 + ks)*64 + l];
      acc = __builtin_amdgcn_mfma_f32_16x16x32_f16(a[ks], b.h, acc, 0, 0, 0);
    }
    u16* dst = (ct < 4) ? Q : Kv;
    int cc = (ct & 3)*16 + row16;
    #pragma unroll
    for (int r = 0; r < 4; r++){
      int node = nBase + wv*16 + g*4 + r;        // D: col=lane&15, row=(lane>>4)*4+r
      if (node < NN) dst[(size_t)node*256 + d*64 + cc] = f2h_u(acc[r]);
    }
  }
}

// ---------------------------------------------------------------------------
// kA: gather + edge dot -> w_ij f16 [E][64] in ws. (R8-validated)
// ---------------------------------------------------------------------------
__global__ __launch_bounds__(256) void kA_dot(
    const u16* __restrict__ Q, const u16* __restrict__ Kv,
    const int* __restrict__ eidx, u16* __restrict__ Wg)
{
  const int wv = threadIdx.x >> 6;
  const int l  = threadIdx.x & 63;
  const int eBase = (blockIdx.x*4 + wv)*16;
  const int er = l >> 2, p = l & 3;
  const int eg = eBase + er;
  const int nj = eidx[eg];        // edge_index[0] = n_j (sender, uses ek)
  const int ni = eidx[EE + eg];   // edge_index[1] = n_i (receiver, uses eq)
  const u16* qb = Q  + (size_t)ni*256 + p*16;
  const u16* kb = Kv + (size_t)nj*256 + p*16;
  float acc16[16];
  #pragma unroll
  for (int j = 0; j < 16; j++) acc16[j] = 0.f;
  #pragma unroll
  for (int dd = 0; dd < 4; dd++){
    uint4 qa = *(const uint4*)(qb + dd*64);
    uint4 qc = *(const uint4*)(qb + dd*64 + 8);
    uint4 ka = *(const uint4*)(kb + dd*64);
    uint4 kc = *(const uint4*)(kb + dd*64 + 8);
    u32 qs[8] = {qa.x,qa.y,qa.z,qa.w,qc.x,qc.y,qc.z,qc.w};
    u32 ks_[8] = {ka.x,ka.y,ka.z,ka.w,kc.x,kc.y,kc.z,kc.w};
    #pragma unroll
    for (int j = 0; j < 8; j++){
      float2 qf = up2(qs[j]), kf = up2(ks_[j]);
      acc16[2*j]   += qf.x * kf.x;
      acc16[2*j+1] += qf.y * kf.y;
    }
  }
  uint4 wlo, whi;
  wlo.x = phh(acc16[0],acc16[1]);   wlo.y = phh(acc16[2],acc16[3]);
  wlo.z = phh(acc16[4],acc16[5]);   wlo.w = phh(acc16[6],acc16[7]);
  whi.x = phh(acc16[8],acc16[9]);   whi.y = phh(acc16[10],acc16[11]);
  whi.z = phh(acc16[12],acc16[13]); whi.w = phh(acc16[14],acc16[15]);
  uint4* dst = (uint4*)(Wg + (size_t)eg*64 + p*16);
  dst[0] = wlo;
  dst[1] = whi;
}

// ---------------------------------------------------------------------------
// k2_mlp v11: EXACT R8 geometry (512 thr / 8 waves, 112KB weights + bias +
// 8x4KB hb in LDS, VGPR~120 no-spill) + two latency micro-fixes:
//  1. 2-way split accumulator chains: (m0·f0+m1·f1)+(m2·f2+m3·f3) — halves
//     the serially-dependent MFMA latency per ct iteration
//  2. s_setprio(1) around MFMA clusters (T5): barrier-free desynced waves =
//     the regime where setprio pays (m191); R8's waves qualify
// ---------------------------------------------------------------------------
#define MW1_4 0
#define MW2_4 1024
#define MT1_4 3072
#define MT2_4 5120

#define K2_LOAD(TF0,TF1,TF2,TF3,WF0,WF1,TIDX)                                   \
{                                                                               \
  const int e_ = (TIDX)*16 + e16;                                               \
  const float* trow_ = T + (size_t)e_*128;                                      \
  float4 a_, b_;                                                                \
  a_ = *(const float4*)(trow_ +  0 + g*8); b_ = *(const float4*)(trow_ +  0 + g*8 + 4); TF0 = pack8(a_,b_); \
  a_ = *(const float4*)(trow_ + 32 + g*8); b_ = *(const float4*)(trow_ + 32 + g*8 + 4); TF1 = pack8(a_,b_); \
  a_ = *(const float4*)(trow_ + 64 + g*8); b_ = *(const float4*)(trow_ + 64 + g*8 + 4); TF2 = pack8(a_,b_); \
  a_ = *(const float4*)(trow_ + 96 + g*8); b_ = *(const float4*)(trow_ + 96 + g*8 + 4); TF3 = pack8(a_,b_); \
  const uint4* wrow_ = (const uint4*)(Wg + (size_t)e_*64);                      \
  WF0.u = wrow_[g];                                                             \
  WF1.u = wrow_[4 + g];                                                         \
}

#define K2_TILE(TF0,TF1,TF2,TF3,WF0,WF1,TIDX)                                   \
{                                                                               \
  /* t-L1 -> hb (split acc chains) */                                           \
  _Pragma("unroll")                                                             \
  for (int ct = 0; ct < 8; ct++){                                               \
    U16 q0,q1,q2,q3;                                                            \
    q0.u = wlds4[MT1_4 + (ct*4+0)*64 + l];                                      \
    q1.u = wlds4[MT1_4 + (ct*4+1)*64 + l];                                      \
    q2.u = wlds4[MT1_4 + (ct*4+2)*64 + l];                                      \
    q3.u = wlds4[MT1_4 + (ct*4+3)*64 + l];                                      \
    f4 Aa = {0.f,0.f,0.f,0.f}, Ab = Aa;                                         \
    __builtin_amdgcn_s_setprio(1);                                              \
    Aa = __builtin_amdgcn_mfma_f32_16x16x32_f16(q0.h, TF0, Aa, 0, 0, 0);        \
    Ab = __builtin_amdgcn_mfma_f32_16x16x32_f16(q1.h, TF1, Ab, 0, 0, 0);        \
    Aa = __builtin_amdgcn_mfma_f32_16x16x32_f16(q2.h, TF2, Aa, 0, 0, 0);        \
    Ab = __builtin_amdgcn_mfma_f32_16x16x32_f16(q3.h, TF3, Ab, 0, 0, 0);        \
    __builtin_amdgcn_s_setprio(0);                                              \
    f4 A = Aa + Ab;                                                             \
    float4 bb = *(const float4*)&bias_lds[256 + ct*16 + g*4];                   \
    uint2 v;                                                                    \
    v.x = phh(fmaxf(A[0]+bb.x,0.f), fmaxf(A[1]+bb.y,0.f));                      \
    v.y = phh(fmaxf(A[2]+bb.z,0.f), fmaxf(A[3]+bb.w,0.f));                      \
    *(uint2*)&myhb[e16*128 + ((ct*16 + g*4) ^ swz)] = v;                        \
  }                                                                             \
  /* t-L2 -> accT (f16 packed, incl. b2t) */                                    \
  uint2 accT[8];                                                                \
  {                                                                             \
    U16 h0,h1,h2,h3;                                                            \
    h0.u = *(const uint4*)&myhb[e16*128 + (( 0 + g*8) ^ swz)];                  \
    h1.u = *(const uint4*)&myhb[e16*128 + ((32 + g*8) ^ swz)];                  \
    h2.u = *(const uint4*)&myhb[e16*128 + ((64 + g*8) ^ swz)];                  \
    h3.u = *(const uint4*)&myhb[e16*128 + ((96 + g*8) ^ swz)];                  \
    _Pragma("unroll")                                                           \
    for (int ct = 0; ct < 8; ct++){                                             \
      U16 q0,q1,q2,q3;                                                          \
      q0.u = wlds4[MT2_4 + (ct*4+0)*64 + l];                                    \
      q1.u = wlds4[MT2_4 + (ct*4+1)*64 + l];                                    \
      q2.u = wlds4[MT2_4 + (ct*4+2)*64 + l];                                    \
      q3.u = wlds4[MT2_4 + (ct*4+3)*64 + l];                                    \
      f4 Xa = {0.f,0.f,0.f,0.f}, Xb = Xa;                                       \
      __builtin_amdgcn_s_setprio(1);                                            \
      Xa = __builtin_amdgcn_mfma_f32_16x16x32_f16(q0.h, h0.h, Xa, 0, 0, 0);     \
      Xb = __builtin_amdgcn_mfma_f32_16x16x32_f16(q1.h, h1.h, Xb, 0, 0, 0);     \
      Xa = __builtin_amdgcn_mfma_f32_16x16x32_f16(q2.h, h2.h, Xa, 0, 0, 0);     \
      Xb = __builtin_amdgcn_mfma_f32_16x16x32_f16(q3.h, h3.h, Xb, 0, 0, 0);     \
      __builtin_amdgcn_s_setprio(0);                                            \
      f4 X = Xa + Xb;                                                           \
      float4 bb = *(const float4*)&bias_lds[384 + ct*16 + g*4];                 \
      accT[ct].x = phh(X[0]+bb.x, X[1]+bb.y);                                   \
      accT[ct].y = phh(X[2]+bb.z, X[3]+bb.w);                                   \
    }                                                                           \
  }                                                                             \
  /* w-L1 -> hb (reuse; same-wave DS in-order => WAR safe) */                   \
  _Pragma("unroll")                                                             \
  for (int ct = 0; ct < 8; ct++){                                               \
    U16 q0,q1;                                                                  \
    q0.u = wlds4[MW1_4 + (ct*2+0)*64 + l];                                      \
    q1.u = wlds4[MW1_4 + (ct*2+1)*64 + l];                                      \
    f4 Ba = {0.f,0.f,0.f,0.f}, Bb = Ba;                                         \
    __builtin_amdgcn_s_setprio(1);                                              \
    Ba = __builtin_amdgcn_mfma_f32_16x16x32_f16(q0.h, WF0.h, Ba, 0, 0, 0);      \
    Bb = __builtin_amdgcn_mfma_f32_16x16x32_f16(q1.h, WF1.h, Bb, 0, 0, 0);      \
    __builtin_amdgcn_s_setprio(0);                                              \
    f4 B = Ba + Bb;                                                             \
    float4 bb = *(const float4*)&bias_lds[0 + ct*16 + g*4];                     \
    uint2 v;                                                                    \
    v.x = phh(fmaxf(B[0]+bb.x,0.f), fmaxf(B[1]+bb.y,0.f));                      \
    v.y = phh(fmaxf(B[2]+bb.z,0.f), fmaxf(B[3]+bb.w,0.f));                      \
    *(uint2*)&myhb[e16*128 + ((ct*16 + g*4) ^ swz)] = v;                        \
  }                                                                             \
  /* w-L2 + fused epilogue */                                                   \
  {                                                                             \
    U16 h0,h1,h2,h3;                                                            \
    h0.u = *(const uint4*)&myhb[e16*128 + (( 0 + g*8) ^ swz)];                  \
    h1.u = *(const uint4*)&myhb[e16*128 + ((32 + g*8) ^ swz)];                  \
    h2.u = *(const uint4*)&myhb[e16*128 + ((64 + g*8) ^ swz)];                  \
    h3.u = *(const uint4*)&myhb[e16*128 + ((96 + g*8) ^ swz)];                  \
    _Pragma("unroll")                                                           \
    for (int ct = 0; ct < 8; ct++){                                             \
      U16 q0,q1,q2,q3;                                                          \
      q0.u = wlds4[MW2_4 + (ct*4+0)*64 + l];                                    \
      q1.u = wlds4[MW2_4 + (ct*4+1)*64 + l];                                    \
      q2.u = wlds4[MW2_4 + (ct*4+2)*64 + l];                                    \
      q3.u = wlds4[MW2_4 + (ct*4+3)*64 + l];                                    \
      f4 Ya = {0.f,0.f,0.f,0.f}, Yb = Ya;                                       \
      __builtin_amdgcn_s_setprio(1);                                            \
      Ya = __builtin_amdgcn_mfma_f32_16x16x32_f16(q0.h, h0.h, Ya, 0, 0, 0);     \
      Yb = __builtin_amdgcn_mfma_f32_16x16x32_f16(q1.h, h1.h, Yb, 0, 0, 0);     \
      Ya = __builtin_amdgcn_mfma_f32_16x16x32_f16(q2.h, h2.h, Ya, 0, 0, 0);     \
      Yb = __builtin_amdgcn_mfma_f32_16x16x32_f16(q3.h, h3.h, Yb, 0, 0, 0);     \
      __builtin_amdgcn_s_setprio(0);                                            \
      float4 bb = *(const float4*)&bias_lds[128 + ct*16 + g*4];                 \
      float2 tlo = up2(accT[ct].x), thi = up2(accT[ct].y);                      \
      float4 o;                                                                 \
      o.x = (Ya[0] + Yb[0] + bb.x) * tlo.x;                                     \
      o.y = (Ya[1] + Yb[1] + bb.y) * tlo.y;                                     \
      o.z = (Ya[2] + Yb[2] + bb.z) * thi.x;                                     \
      o.w = (Ya[3] + Yb[3] + bb.w) * thi.y;                                     \
      *(float4*)&out[(size_t)((TIDX)*16 + e16)*128 + ct*16 + g*4] = o;          \
    }                                                                           \
  }                                                                             \
}

__global__ __launch_bounds__(512, 2) void k2_mlp(
    const u16* __restrict__ Wg, const float* __restrict__ T,
    const u16* __restrict__ wsrc,           // pack + 65536 (mw1,mw2,mt1,mt2 linear)
    const float* __restrict__ b1w, const float* __restrict__ b2w,
    const float* __restrict__ b1t, const float* __restrict__ b2t,
    float* __restrict__ out, int nTiles)
{
  __shared__ alignas(16) u16   wlds[57344];    // 112KB packed MLP weights
  __shared__ alignas(16) float bias_lds[512];  // b1w|b2w|b1t|b2t
  __shared__ alignas(16) u16   hb[8][2048];    // 4KB hidden buffer per wave
  {
    const uint4* src = (const uint4*)wsrc;
    uint4* dst = (uint4*)wlds;
    #pragma unroll
    for (int i = 0; i < 14; i++)
      dst[threadIdx.x + i*512] = src[threadIdx.x + i*512];
    int t = threadIdx.x;
    float bv = (t < 128) ? b1w[t] : (t < 256) ? b2w[t-128]
             : (t < 384) ? b1t[t-256] : b2t[t-384];
    bias_lds[t] = bv;
  }
  __syncthreads();                             // only barrier in the kernel

  const int wv = threadIdx.x >> 6;
  const int l  = threadIdx.x & 63;
  const int e16 = l & 15, g = l >> 4;
  const int swz = (e16 & 7) << 3;
  const uint4* wlds4 = (const uint4*)wlds;
  u16* myhb = hb[wv];
  const int tStride = gridDim.x << 3;

  h8 tA0, tA1, tA2, tA3;  U16 wA0, wA1;
  h8 tB0, tB1, tB2, tB3;  U16 wB0, wB1;

  int t = blockIdx.x*8 + wv;                   // always < nTiles (2048 < 20000)
  K2_LOAD(tA0,tA1,tA2,tA3,wA0,wA1,t)
  while (true){
    int tn = t + tStride;
    bool v1 = tn < nTiles;
    if (v1) { K2_LOAD(tB0,tB1,tB2,tB3,wB0,wB1,tn) }
    K2_TILE(tA0,tA1,tA2,tA3,wA0,wA1,t)
    if (!v1) return;
    int tn2 = tn + tStride;
    bool v2 = tn2 < nTiles;
    if (v2) { K2_LOAD(tA0,tA1,tA2,tA3,wA0,wA1,tn2) }
    K2_TILE(tB0,tB1,tB2,tB3,wB0,wB1,tn)
    if (!v2) return;
    t = tn2;
  }
}

extern "C" void kernel_launch(void* const* d_in, const int* in_sizes, int n_in,
                              void* d_out, int out_size, void* d_ws, size_t ws_size,
                              hipStream_t stream) {
  const float* X   = (const float*)d_in[0];
  const float* T   = (const float*)d_in[1];
  const int*   EI  = (const int*)  d_in[2];
  const float* Wq  = (const float*)d_in[3];
  const float* Wk  = (const float*)d_in[4];
  const float* w1w = (const float*)d_in[5];
  const float* b1w = (const float*)d_in[6];
  const float* w2w = (const float*)d_in[7];
  const float* b2w = (const float*)d_in[8];
  const float* w1t = (const float*)d_in[9];
  const float* b1t = (const float*)d_in[10];
  const float* w2t = (const float*)d_in[11];
  const float* b2t = (const float*)d_in[12];
  float* out = (float*)d_out;

  u16* ws   = (u16*)d_ws;
  u16* pack = ws;                           // 240 KB packed weights
  u16* Q    = ws + 122880;                  // [N][256] f16 (10.24 MB)
  u16* Kv   = Q + (size_t)NN*256;           // [N][256] f16 (10.24 MB)
  u16* Wg   = Kv + (size_t)NN*256;          // [E][64] f16  (40.96 MB)

  k0_pack<<<64, 256, 0, stream>>>(Wq, Wk, w1w, w2w, w1t, w2t, pack);
  k1_proj<<<dim3((NN + 63)/64, 4), 256, 0, stream>>>(X, pack, Q, Kv);
  kA_dot<<<EE/64, 256, 0, stream>>>(Q, Kv, EI, Wg);
  k2_mlp<<<256, 512, 0, stream>>>(Wg, T, (const u16*)(ws + 65536),
      b1w, b2w, b1t, b2t, out, EE/16);
}